// Round 1
// baseline (170.937 us; speedup 1.0000x reference)
//
#include <hip/hip_runtime.h>

// ColPali2Loss: sv in-batch softmax CE + mv MaxSim margin loss.
// B=64, Nq=32, Ns=1024, D=128. Outputs: [sv_loss, mv_loss, total] f32.

typedef __attribute__((ext_vector_type(8))) short short8;
typedef __attribute__((ext_vector_type(4))) float f32x4;

static __device__ __forceinline__ unsigned short f2bf(float f) {
  unsigned int u = __float_as_uint(f);
  u += 0x7fffu + ((u >> 16) & 1u);   // RNE to bf16
  return (unsigned short)(u >> 16);
}

// ---------------- single-vector loss (tiny, one block) ----------------
__global__ void sv_kernel(const float* __restrict__ qs,
                          const float* __restrict__ ds,
                          float* __restrict__ out_sv) {
  __shared__ float sc[64][64];
  const int tid = threadIdx.x;  // 256
  for (int p = tid; p < 4096; p += 256) {
    const int b = p >> 6, c = p & 63;
    const float4* qa = (const float4*)(qs + b * 128);
    const float4* da = (const float4*)(ds + c * 128);
    float acc = 0.f;
#pragma unroll
    for (int i = 0; i < 32; ++i) {
      const float4 x = qa[i], y = da[i];
      acc += x.x * y.x + x.y * y.y + x.z * y.z + x.w * y.w;
    }
    sc[b][c] = acc;
  }
  __syncthreads();
  if (tid < 64) {
    float m = -3.0e38f;
    for (int c = 0; c < 64; ++c) m = fmaxf(m, sc[tid][c]);
    float s = 0.f;
    for (int c = 0; c < 64; ++c) s += expf(sc[tid][c] - m);
    float lp = sc[tid][tid] - (m + logf(s));
    lp += __shfl_xor(lp, 1);
    lp += __shfl_xor(lp, 2);
    lp += __shfl_xor(lp, 4);
    lp += __shfl_xor(lp, 8);
    lp += __shfl_xor(lp, 16);
    lp += __shfl_xor(lp, 32);
    if (tid == 0) *out_sv = -lp / 64.0f;
  }
}

// ---------------- multi-vector MaxSim scores ----------------
// Block: 256 threads (4 waves). Covers 128 rows (4 b's) x one doc c.
// Iterates s in 16 tiles of 64; d tile staged f32->bf16 into swizzled LDS.
__global__ __launch_bounds__(256, 4) void mv_gemm_kernel(
    const float* __restrict__ qm, const float* __restrict__ dm,
    float* __restrict__ scores) {
  __shared__ unsigned char dtb[64 * 256];  // 64 s-rows x 128 bf16 (swizzled)
  __shared__ float rowmax[128];

  const int c   = blockIdx.y;
  const int rb  = blockIdx.x;   // 0..15
  const int tid = threadIdx.x;
  const int ln  = tid & 63;
  const int wv  = tid >> 6;
  const int lrow = ln & 15;     // A row / B col within fragment
  const int lkg  = ln >> 4;     // k-group

  // q fragments: 2 row-tiles x 4 k-chunks, held in registers all kernel.
  short8 qf[2][4];
#pragma unroll
  for (int rt = 0; rt < 2; ++rt) {
    const int row = rb * 128 + wv * 32 + rt * 16 + lrow;  // (b,n) flattened
    const float* qp = qm + (size_t)row * 128 + lkg * 8;
#pragma unroll
    for (int kk = 0; kk < 4; ++kk) {
      const float4 a = *(const float4*)(qp + kk * 32);
      const float4 b = *(const float4*)(qp + kk * 32 + 4);
      short8 f;
      f[0] = (short)f2bf(a.x); f[1] = (short)f2bf(a.y);
      f[2] = (short)f2bf(a.z); f[3] = (short)f2bf(a.w);
      f[4] = (short)f2bf(b.x); f[5] = (short)f2bf(b.y);
      f[6] = (short)f2bf(b.z); f[7] = (short)f2bf(b.w);
      qf[rt][kk] = f;
    }
  }

  f32x4 maxv[2];
#pragma unroll
  for (int rt = 0; rt < 2; ++rt)
#pragma unroll
    for (int r = 0; r < 4; ++r) maxv[rt][r] = -3.0e38f;

  const float* dbase = dm + (size_t)c * 1024 * 128;

  for (int t = 0; t < 16; ++t) {
    __syncthreads();  // protect previous tile's LDS reads
#pragma unroll
    for (int i = 0; i < 4; ++i) {
      const int ch = tid + i * 256;       // 1024 16B-chunks
      const int s  = ch >> 4;             // 0..63
      const int kc = ch & 15;             // 8 floats each
      const float* p = dbase + (size_t)(t * 64 + s) * 128 + kc * 8;
      const float4 a = *(const float4*)p;
      const float4 b = *(const float4*)(p + 4);
      short8 w;
      w[0] = (short)f2bf(a.x); w[1] = (short)f2bf(a.y);
      w[2] = (short)f2bf(a.z); w[3] = (short)f2bf(a.w);
      w[4] = (short)f2bf(b.x); w[5] = (short)f2bf(b.y);
      w[6] = (short)f2bf(b.z); w[7] = (short)f2bf(b.w);
      *(short8*)(dtb + s * 256 + ((kc * 16) ^ ((s & 7) << 4))) = w;
    }
    __syncthreads();

#pragma unroll
    for (int cc = 0; cc < 4; ++cc) {
      const int s = cc * 16 + lrow;
      short8 df[4];
#pragma unroll
      for (int kk = 0; kk < 4; ++kk)
        df[kk] = *(const short8*)(dtb + s * 256 +
                                  ((kk * 64 + lkg * 16) ^ ((s & 7) << 4)));
#pragma unroll
      for (int rt = 0; rt < 2; ++rt) {
        f32x4 acc = {0.f, 0.f, 0.f, 0.f};
#pragma unroll
        for (int kk = 0; kk < 4; ++kk)
          acc = __builtin_amdgcn_mfma_f32_16x16x32_bf16(qf[rt][kk], df[kk],
                                                        acc, 0, 0, 0);
        // K complete for these 16 cols -> fold into running row-max
#pragma unroll
        for (int r = 0; r < 4; ++r) maxv[rt][r] = fmaxf(maxv[rt][r], acc[r]);
      }
    }
  }

  // max over the 16 column-lanes (xor bits 0..3 stay within k-group)
#pragma unroll
  for (int rt = 0; rt < 2; ++rt)
#pragma unroll
    for (int r = 0; r < 4; ++r) {
      float v = maxv[rt][r];
      v = fmaxf(v, __shfl_xor(v, 1));
      v = fmaxf(v, __shfl_xor(v, 2));
      v = fmaxf(v, __shfl_xor(v, 4));
      v = fmaxf(v, __shfl_xor(v, 8));
      maxv[rt][r] = v;
    }

  // C/D layout: row = lkg*4 + r, col = lrow
  if (lrow == 0) {
#pragma unroll
    for (int rt = 0; rt < 2; ++rt)
#pragma unroll
      for (int r = 0; r < 4; ++r)
        rowmax[wv * 32 + rt * 16 + lkg * 4 + r] = maxv[rt][r];
  }
  __syncthreads();

  // sum the 32 per-n maxes for each of the 4 b's in this row-block
  if (tid < 128) {
    float v = rowmax[tid];
    v += __shfl_xor(v, 1);
    v += __shfl_xor(v, 2);
    v += __shfl_xor(v, 4);
    v += __shfl_xor(v, 8);
    v += __shfl_xor(v, 16);
    if ((tid & 31) == 0) {
      const int b = rb * 4 + (tid >> 5);
      scores[b * 64 + c] = v;
    }
  }
}

// ---------------- final: margin loss + combine ----------------
__global__ void final_kernel(const float* __restrict__ scores,
                             const float* __restrict__ sv_ptr,
                             float* __restrict__ out) {
  const int b = threadIdx.x;  // 64
  const float pos = scores[b * 64 + b];
  float neg = -3.0e38f;
  for (int c = 0; c < 64; ++c) {
    float v = scores[b * 64 + c] - (c == b ? 1.0e6f : 0.0f);
    neg = fmaxf(neg, v);
  }
  float t = neg - pos;
  float sp = fmaxf(t, 0.f) + log1pf(expf(-fabsf(t)));  // stable softplus
  sp += __shfl_xor(sp, 1);
  sp += __shfl_xor(sp, 2);
  sp += __shfl_xor(sp, 4);
  sp += __shfl_xor(sp, 8);
  sp += __shfl_xor(sp, 16);
  sp += __shfl_xor(sp, 32);
  if (b == 0) {
    const float mv = sp / 64.0f;
    const float sv = *sv_ptr;
    out[0] = sv;
    out[1] = mv;
    out[2] = 0.5f * sv + 0.5f * mv;
  }
}

extern "C" void kernel_launch(void* const* d_in, const int* in_sizes, int n_in,
                              void* d_out, int out_size, void* d_ws,
                              size_t ws_size, hipStream_t stream) {
  const float* qs = (const float*)d_in[0];  // (64,128)
  const float* ds = (const float*)d_in[1];  // (64,128)
  const float* qm = (const float*)d_in[2];  // (64,32,128)
  const float* dm = (const float*)d_in[3];  // (64,1024,128)
  float* out = (float*)d_out;

  float* scores = (float*)d_ws;       // 64*64 f32
  float* sv     = scores + 4096;      // 1 f32

  sv_kernel<<<1, 256, 0, stream>>>(qs, ds, sv);
  mv_gemm_kernel<<<dim3(16, 64), 256, 0, stream>>>(qm, dm, scores);
  final_kernel<<<1, 64, 0, stream>>>(scores, sv, out);
}

// Round 5
// 51.431 us; speedup vs baseline: 3.3236x; 3.3236x over previous
//
#include <hip/hip_runtime.h>

// ColPali2Loss: sv in-batch softmax CE + mv MaxSim margin loss.
// B=64, Nq=32, Ns=1024, D=128. Outputs: [sv_loss, mv_loss, total] f32.

typedef __attribute__((ext_vector_type(8))) short short8;
typedef __attribute__((ext_vector_type(4))) float f32x4;

static __device__ __forceinline__ unsigned short f2bf(float f) {
  unsigned int u = __float_as_uint(f);
  u += 0x7fffu + ((u >> 16) & 1u);  // RNE to bf16
  return (unsigned short)(u >> 16);
}

static __device__ __forceinline__ void g2l16(const void* g, void* l) {
  __builtin_amdgcn_global_load_lds(
      (const __attribute__((address_space(1))) unsigned int*)g,
      (__attribute__((address_space(3))) unsigned int*)l, 16, 0, 0);
}

// ---------------- pre-convert: dm -> swizzled bf16, qm -> linear bf16 -----
// dmb layout (bytes): c*262144 + s*256 + ((kc*16) ^ ((s&7)<<4)), kc = 16B grp
// qmb layout: row*256 + k*2
// dm groups: 64 docs * 1024 s * 16 kc = 1048576  (r3/r4 bug: used 524288)
__global__ void convert_kernel(const float* __restrict__ qm,
                               const float* __restrict__ dm,
                               unsigned char* __restrict__ dmb,
                               unsigned short* __restrict__ qmb) {
  const int NDM = 1048576;
  const int NT = NDM + 32768;  // + qm 16B-groups
  for (int g = blockIdx.x * 256 + threadIdx.x; g < NT;
       g += gridDim.x * 256) {
    const float* src;
    unsigned char* dst;
    if (g < NDM) {
      const int c = g >> 14;  // 16384 groups per doc
      const int r = g & 16383;
      const int s = r >> 4;
      const int kc = r & 15;
      src = dm + ((size_t)c * 131072 + (size_t)s * 128 + kc * 8);
      dst = dmb + ((size_t)c * 262144 + s * 256 +
                   ((kc * 16) ^ ((s & 7) << 4)));
    } else {
      const int gg = g - NDM;
      const int row = gg >> 4;
      const int kc = gg & 15;
      src = qm + (size_t)row * 128 + kc * 8;
      dst = (unsigned char*)(qmb + (size_t)row * 128 + kc * 8);
    }
    const float4 a = *(const float4*)src;
    const float4 b = *(const float4*)(src + 4);
    short8 w;
    w[0] = (short)f2bf(a.x); w[1] = (short)f2bf(a.y);
    w[2] = (short)f2bf(a.z); w[3] = (short)f2bf(a.w);
    w[4] = (short)f2bf(b.x); w[5] = (short)f2bf(b.y);
    w[6] = (short)f2bf(b.z); w[7] = (short)f2bf(b.w);
    *(short8*)dst = w;
  }
}

// ---------------- fused mv GEMM (+ sv in by==64 blocks) ----------------
// mv blocks: 256 threads / 4 waves; 256 rows x 1 doc c; 16 tiles of 64 s.
// Staging via global_load_lds from pre-swizzled dmb (linear LDS dest),
// double-buffered.
__global__ __launch_bounds__(256, 2) void mv_kernel(
    const unsigned short* __restrict__ qmb,
    const unsigned char* __restrict__ dmb,
    const float* __restrict__ qs, const float* __restrict__ ds,
    float* __restrict__ scores, float* __restrict__ svp) {
  __shared__ __align__(16) unsigned char smem[33792];

  const int tid = threadIdx.x;
  const int ln = tid & 63;
  const int wv = tid >> 6;

  if (blockIdx.y == 64) {
    // ---- sv block: rows 8*rb .. 8*rb+7 of the 64x64 score matrix ----
    const int rb = blockIdx.x;  // 0..7
    float* dl = (float*)smem;   // [64][129] padded f32
    for (int i = tid; i < 8192; i += 256)
      dl[(i >> 7) * 129 + (i & 127)] = ds[i];
    __syncthreads();
    const int cc = ln;  // candidate doc = lane
    for (int rr = 0; rr < 2; ++rr) {
      const int row = rb * 8 + wv * 2 + rr;
      const float* q = qs + (size_t)row * 128;
      float acc = 0.f;
#pragma unroll
      for (int k = 0; k < 128; ++k) acc += q[k] * dl[cc * 129 + k];
      float m = acc;
      for (int d = 1; d < 64; d <<= 1) m = fmaxf(m, __shfl_xor(m, d));
      float e = expf(acc - m);
      float ssum = e;
      for (int d = 1; d < 64; d <<= 1) ssum += __shfl_xor(ssum, d);
      const float lp = acc - m - logf(ssum);
      const float diag = __shfl(lp, row);
      if (ln == 0) svp[row] = -diag;
    }
    return;
  }

  const int c = blockIdx.y;
  const int rb = blockIdx.x;  // 0..7 (256 rows each)
  const int lrow = ln & 15;
  const int lkg = ln >> 4;

  // A fragments: 4 row-tiles x 4 k-chunks, registers all kernel.
  short8 qf[4][4];
#pragma unroll
  for (int rt = 0; rt < 4; ++rt) {
    const int row = rb * 256 + wv * 64 + rt * 16 + lrow;
    const unsigned short* qp = qmb + (size_t)row * 128 + lkg * 8;
#pragma unroll
    for (int kk = 0; kk < 4; ++kk)
      qf[rt][kk] = *(const short8*)(qp + kk * 32);
  }

  f32x4 maxv[4];
#pragma unroll
  for (int rt = 0; rt < 4; ++rt)
#pragma unroll
    for (int r = 0; r < 4; ++r) maxv[rt][r] = -3.0e38f;

  const unsigned char* dbase = dmb + (size_t)c * 262144;
  float* rowmax = (float*)(smem + 32768);

  // prologue: stage tile 0
#pragma unroll
  for (int i = 0; i < 4; ++i) {
    const int chunk = wv * 4 + i;
    g2l16(dbase + chunk * 1024 + ln * 16, smem + chunk * 1024);
  }
  __syncthreads();

  for (int t = 0; t < 16; ++t) {
    const unsigned char* cur = smem + (t & 1) * 16384;
    if (t < 15) {
      unsigned char* nxt = smem + ((t + 1) & 1) * 16384;
      const unsigned char* gsrc = dbase + (t + 1) * 16384;
#pragma unroll
      for (int i = 0; i < 4; ++i) {
        const int chunk = wv * 4 + i;
        g2l16(gsrc + chunk * 1024 + ln * 16, nxt + chunk * 1024);
      }
    }
#pragma unroll
    for (int cc = 0; cc < 4; ++cc) {
      const int s = cc * 16 + lrow;
      const unsigned char* bp = cur + s * 256;
      const int swz = (s & 7) << 4;
      short8 df[4];
#pragma unroll
      for (int kk = 0; kk < 4; ++kk)
        df[kk] = *(const short8*)(bp + ((kk * 64 + lkg * 16) ^ swz));
#pragma unroll
      for (int rt = 0; rt < 4; ++rt) {
        f32x4 a = {0.f, 0.f, 0.f, 0.f};
#pragma unroll
        for (int kk = 0; kk < 4; ++kk)
          a = __builtin_amdgcn_mfma_f32_16x16x32_bf16(qf[rt][kk], df[kk], a,
                                                      0, 0, 0);
#pragma unroll
        for (int r = 0; r < 4; ++r) maxv[rt][r] = fmaxf(maxv[rt][r], a[r]);
      }
    }
    __syncthreads();  // drains vmcnt (next tile staged) + all reads of cur done
  }

  // max over 16 s-column lanes (C/D: col=lrow, row=lkg*4+r)
#pragma unroll
  for (int rt = 0; rt < 4; ++rt)
#pragma unroll
    for (int r = 0; r < 4; ++r) {
      float v = maxv[rt][r];
      v = fmaxf(v, __shfl_xor(v, 1));
      v = fmaxf(v, __shfl_xor(v, 2));
      v = fmaxf(v, __shfl_xor(v, 4));
      v = fmaxf(v, __shfl_xor(v, 8));
      if (lrow == 0) rowmax[wv * 64 + rt * 16 + lkg * 4 + r] = v;
    }
  __syncthreads();

  // sum the 32 per-n maxes for each of the 8 b's in this row-block
  {
    float v = rowmax[tid];
    v += __shfl_xor(v, 1);
    v += __shfl_xor(v, 2);
    v += __shfl_xor(v, 4);
    v += __shfl_xor(v, 8);
    v += __shfl_xor(v, 16);
    if ((tid & 31) == 0) {
      const int b = rb * 8 + (tid >> 5);
      scores[b * 64 + c] = v;
    }
  }
}

// ---------------- final: sv mean + margin loss + combine ----------------
__global__ void final_kernel(const float* __restrict__ scores,
                             const float* __restrict__ svp,
                             float* __restrict__ out) {
  const int b = threadIdx.x;  // 64
  float sv = svp[b];
  for (int d = 1; d < 64; d <<= 1) sv += __shfl_xor(sv, d);
  sv *= (1.0f / 64.0f);

  const float pos = scores[b * 64 + b];
  float neg = -3.0e38f;
  for (int c = 0; c < 64; ++c) {
    float v = scores[b * 64 + c] - (c == b ? 1.0e6f : 0.0f);
    neg = fmaxf(neg, v);
  }
  const float t = neg - pos;
  float sp = fmaxf(t, 0.f) + log1pf(expf(-fabsf(t)));
  for (int d = 1; d < 64; d <<= 1) sp += __shfl_xor(sp, d);
  if (b == 0) {
    const float mvl = sp / 64.0f;
    out[0] = sv;
    out[1] = mvl;
    out[2] = 0.5f * sv + 0.5f * mvl;
  }
}

// ======================= fallback (round-1, passing) =======================
__global__ void sv_kernel_fb(const float* __restrict__ qs,
                             const float* __restrict__ ds,
                             float* __restrict__ out_sv) {
  __shared__ float sc[64][64];
  const int tid = threadIdx.x;
  for (int p = tid; p < 4096; p += 256) {
    const int b = p >> 6, c = p & 63;
    const float4* qa = (const float4*)(qs + b * 128);
    const float4* da = (const float4*)(ds + c * 128);
    float acc = 0.f;
#pragma unroll
    for (int i = 0; i < 32; ++i) {
      const float4 x = qa[i], y = da[i];
      acc += x.x * y.x + x.y * y.y + x.z * y.z + x.w * y.w;
    }
    sc[b][c] = acc;
  }
  __syncthreads();
  if (tid < 64) {
    float m = -3.0e38f;
    for (int c = 0; c < 64; ++c) m = fmaxf(m, sc[tid][c]);
    float s = 0.f;
    for (int c = 0; c < 64; ++c) s += expf(sc[tid][c] - m);
    float lp = sc[tid][tid] - (m + logf(s));
    for (int d = 1; d < 64; d <<= 1) lp += __shfl_xor(lp, d);
    if (tid == 0) *out_sv = -lp / 64.0f;
  }
}

__global__ __launch_bounds__(256, 4) void mv_gemm_fb(
    const float* __restrict__ qm, const float* __restrict__ dm,
    float* __restrict__ scores) {
  __shared__ unsigned char dtb[64 * 256];
  __shared__ float rowmax[128];
  const int c = blockIdx.y;
  const int rb = blockIdx.x;
  const int tid = threadIdx.x;
  const int ln = tid & 63;
  const int wv = tid >> 6;
  const int lrow = ln & 15;
  const int lkg = ln >> 4;
  short8 qf[2][4];
#pragma unroll
  for (int rt = 0; rt < 2; ++rt) {
    const int row = rb * 128 + wv * 32 + rt * 16 + lrow;
    const float* qp = qm + (size_t)row * 128 + lkg * 8;
#pragma unroll
    for (int kk = 0; kk < 4; ++kk) {
      const float4 a = *(const float4*)(qp + kk * 32);
      const float4 b = *(const float4*)(qp + kk * 32 + 4);
      short8 f;
      f[0] = (short)f2bf(a.x); f[1] = (short)f2bf(a.y);
      f[2] = (short)f2bf(a.z); f[3] = (short)f2bf(a.w);
      f[4] = (short)f2bf(b.x); f[5] = (short)f2bf(b.y);
      f[6] = (short)f2bf(b.z); f[7] = (short)f2bf(b.w);
      qf[rt][kk] = f;
    }
  }
  f32x4 maxv[2];
#pragma unroll
  for (int rt = 0; rt < 2; ++rt)
#pragma unroll
    for (int r = 0; r < 4; ++r) maxv[rt][r] = -3.0e38f;
  const float* dbase = dm + (size_t)c * 1024 * 128;
  for (int t = 0; t < 16; ++t) {
    __syncthreads();
#pragma unroll
    for (int i = 0; i < 4; ++i) {
      const int ch = tid + i * 256;
      const int s = ch >> 4;
      const int kc = ch & 15;
      const float* p = dbase + (size_t)(t * 64 + s) * 128 + kc * 8;
      const float4 a = *(const float4*)p;
      const float4 b = *(const float4*)(p + 4);
      short8 w;
      w[0] = (short)f2bf(a.x); w[1] = (short)f2bf(a.y);
      w[2] = (short)f2bf(a.z); w[3] = (short)f2bf(a.w);
      w[4] = (short)f2bf(b.x); w[5] = (short)f2bf(b.y);
      w[6] = (short)f2bf(b.z); w[7] = (short)f2bf(b.w);
      *(short8*)(dtb + s * 256 + ((kc * 16) ^ ((s & 7) << 4))) = w;
    }
    __syncthreads();
#pragma unroll
    for (int cc = 0; cc < 4; ++cc) {
      const int s = cc * 16 + lrow;
      short8 df[4];
#pragma unroll
      for (int kk = 0; kk < 4; ++kk)
        df[kk] = *(const short8*)(dtb + s * 256 +
                                  ((kk * 64 + lkg * 16) ^ ((s & 7) << 4)));
#pragma unroll
      for (int rt = 0; rt < 2; ++rt) {
        f32x4 acc = {0.f, 0.f, 0.f, 0.f};
#pragma unroll
        for (int kk = 0; kk < 4; ++kk)
          acc = __builtin_amdgcn_mfma_f32_16x16x32_bf16(qf[rt][kk], df[kk],
                                                        acc, 0, 0, 0);
#pragma unroll
        for (int r = 0; r < 4; ++r) maxv[rt][r] = fmaxf(maxv[rt][r], acc[r]);
      }
    }
  }
#pragma unroll
  for (int rt = 0; rt < 2; ++rt)
#pragma unroll
    for (int r = 0; r < 4; ++r) {
      float v = maxv[rt][r];
      v = fmaxf(v, __shfl_xor(v, 1));
      v = fmaxf(v, __shfl_xor(v, 2));
      v = fmaxf(v, __shfl_xor(v, 4));
      v = fmaxf(v, __shfl_xor(v, 8));
      maxv[rt][r] = v;
    }
  if (lrow == 0) {
#pragma unroll
    for (int rt = 0; rt < 2; ++rt)
#pragma unroll
      for (int r = 0; r < 4; ++r)
        rowmax[wv * 32 + rt * 16 + lkg * 4 + r] = maxv[rt][r];
  }
  __syncthreads();
  if (tid < 128) {
    float v = rowmax[tid];
    v += __shfl_xor(v, 1);
    v += __shfl_xor(v, 2);
    v += __shfl_xor(v, 4);
    v += __shfl_xor(v, 8);
    v += __shfl_xor(v, 16);
    if ((tid & 31) == 0) scores[(rb * 4 + (tid >> 5)) * 64 + c] = v;
  }
}

__global__ void final_fb(const float* __restrict__ scores,
                         const float* __restrict__ sv_ptr,
                         float* __restrict__ out) {
  const int b = threadIdx.x;
  const float pos = scores[b * 64 + b];
  float neg = -3.0e38f;
  for (int c = 0; c < 64; ++c) {
    float v = scores[b * 64 + c] - (c == b ? 1.0e6f : 0.0f);
    neg = fmaxf(neg, v);
  }
  const float t = neg - pos;
  float sp = fmaxf(t, 0.f) + log1pf(expf(-fabsf(t)));
  for (int d = 1; d < 64; d <<= 1) sp += __shfl_xor(sp, d);
  if (b == 0) {
    const float mvl = sp / 64.0f;
    const float sv = *sv_ptr;
    out[0] = sv;
    out[1] = mvl;
    out[2] = 0.5f * sv + 0.5f * mvl;
  }
}

extern "C" void kernel_launch(void* const* d_in, const int* in_sizes, int n_in,
                              void* d_out, int out_size, void* d_ws,
                              size_t ws_size, hipStream_t stream) {
  const float* qs = (const float*)d_in[0];  // (64,128)
  const float* ds = (const float*)d_in[1];  // (64,128)
  const float* qm = (const float*)d_in[2];  // (64,32,128)
  const float* dm = (const float*)d_in[3];  // (64,1024,128)
  float* out = (float*)d_out;

  const size_t NEED = 16777216u + 524288u + 16384u + 256u;
  if (ws_size >= NEED) {
    unsigned char* dmb = (unsigned char*)d_ws;                 // 16 MiB
    unsigned short* qmb = (unsigned short*)(dmb + 16777216u);  // 512 KiB
    float* scores = (float*)(dmb + 16777216u + 524288u);       // 16 KiB
    float* svp = scores + 4096;                                // 64 f32
    convert_kernel<<<2048, 256, 0, stream>>>(qm, dm, dmb, qmb);
    mv_kernel<<<dim3(8, 65), 256, 0, stream>>>(qmb, dmb, qs, ds, scores, svp);
    final_kernel<<<1, 64, 0, stream>>>(scores, svp, out);
  } else {
    float* scores = (float*)d_ws;
    float* sv = scores + 4096;
    sv_kernel_fb<<<1, 256, 0, stream>>>(qs, ds, sv);
    mv_gemm_fb<<<dim3(16, 64), 256, 0, stream>>>(qm, dm, scores);
    final_fb<<<1, 64, 0, stream>>>(scores, sv, out);
  }
}